// Round 1
// baseline (472.649 us; speedup 1.0000x reference)
//
#include <hip/hip_runtime.h>

#define EPSF 1e-12f

__device__ __forceinline__ float tanh_fast(float x) {
    x = fminf(fmaxf(x, -15.f), 15.f);
    float e = __expf(2.f * x);
    return (e - 1.f) / (e + 1.f);
}

// out[:, :ndof] = v ; out[:, ndof:] = (f_ext - Cdiag*v) / Mdiag   (C, M diagonal in this problem)
__global__ void k_init(const float* __restrict__ x, const float* __restrict__ C,
                       const float* __restrict__ Mff, const float* __restrict__ fext,
                       float* __restrict__ out, int B, int ndof) {
    int idx = blockIdx.x * blockDim.x + threadIdx.x;
    if (idx >= B * ndof) return;
    int b = idx / ndof;
    int d = idx - b * ndof;
    size_t row = (size_t)b * (size_t)(2 * ndof);
    float vd = x[row + ndof + d];
    float cd = C[(size_t)d * ndof + d];
    float md = Mff[(size_t)d * ndof + d];
    out[row + d] = vd;
    out[row + ndof + d] = (fext[d] - cd * vd) * __builtin_amdgcn_rcpf(md);
}

// one thread per (batch, spring): strains -> MLP fwd -> MLP bwd -> strain adjoints -> atomic scatter
__global__ __launch_bounds__(256) void k_force(
    const float* __restrict__ x,
    const float* __restrict__ W1, const float* __restrict__ b1,
    const float* __restrict__ W2, const float* __restrict__ b2,
    const float* __restrict__ W3, const float* __restrict__ b3,
    const float* __restrict__ Mff,
    const float* __restrict__ l0e,
    const float* __restrict__ d1i, const float* __restrict__ d2i,
    const int* __restrict__ springs,
    float* __restrict__ out,
    int B, int S, int ndof, int nodal)
{
    __shared__ __align__(16) float sW2[64 * 64];
    __shared__ float sW1[5 * 64];
    __shared__ float sB1[64];
    __shared__ float sB2[64];
    __shared__ float sW3[64];
    {
        int t = threadIdx.x;
        for (int u = t; u < 64 * 64; u += 256) sW2[u] = W2[u];
        for (int u = t; u < 5 * 64; u += 256) sW1[u] = W1[u];
        if (t < 64) { sB1[t] = b1[t]; sB2[t] = b2[t]; sW3[t] = W3[t]; }
    }
    __syncthreads();

    int tid = blockIdx.x * 256 + threadIdx.x;
    if (tid >= B * S) return;
    int b = tid / S;
    int s = tid - b * S;

    const int* spr = springs + 5 * s;
    int ni = spr[0], nj = spr[1], nk = spr[2], iep = spr[3], ien = spr[4];

    const float* q = x + (size_t)b * (size_t)(2 * ndof);
    float xi0 = q[3*ni+0], xi1 = q[3*ni+1], xi2 = q[3*ni+2];
    float xj0 = q[3*nj+0], xj1 = q[3*nj+1], xj2 = q[3*nj+2];
    float xk0 = q[3*nk+0], xk1 = q[3*nk+1], xk2 = q[3*nk+2];
    float thp = q[nodal + iep], thn = q[nodal + ien];
    float l0p = l0e[iep], l0n = l0e[ien];
    float d1p0 = d1i[3*iep+0], d1p1 = d1i[3*iep+1], d1p2 = d1i[3*iep+2];
    float d2p0 = d2i[3*iep+0], d2p1 = d2i[3*iep+1], d2p2 = d2i[3*iep+2];
    float d1n0 = d1i[3*ien+0], d1n1 = d1i[3*ien+1], d1n2 = d1i[3*ien+2];
    float d2n0 = d2i[3*ien+0], d2n1 = d2i[3*ien+1], d2n2 = d2i[3*ien+2];

    // ---- forward strains (matches reference incl. eps placement) ----
    float ep0 = xj0-xi0, ep1 = xj1-xi1, ep2 = xj2-xi2;
    float en0 = xk0-xj0, en1 = xk1-xj1, en2 = xk2-xj2;
    float lp = sqrtf(ep0*ep0 + ep1*ep1 + ep2*ep2);
    float ln = sqrtf(en0*en0 + en1*en1 + en2*en2);
    float ilp = 1.f/(lp + EPSF), iln = 1.f/(ln + EPSF);
    float tp0 = ep0*ilp, tp1 = ep1*ilp, tp2 = ep2*ilp;
    float tn0 = en0*iln, tn1 = en1*iln, tn2 = en2*iln;
    float cdot = tp0*tn0 + tp1*tn1 + tp2*tn2;
    float idenom = 1.f/(1.f + cdot + EPSF);
    float cr0 = tp1*tn2 - tp2*tn1;
    float cr1 = tp2*tn0 - tp0*tn2;
    float cr2 = tp0*tn1 - tp1*tn0;
    float kb0 = 2.f*cr0*idenom, kb1 = 2.f*cr1*idenom, kb2 = 2.f*cr2*idenom;
    float cp, sp; __sincosf(thp, &sp, &cp);
    float cn, sn; __sincosf(thn, &sn, &cn);
    float m1p0 = cp*d1p0 + sp*d2p0, m1p1 = cp*d1p1 + sp*d2p1, m1p2 = cp*d1p2 + sp*d2p2;
    float m2p0 = cp*d2p0 - sp*d1p0, m2p1 = cp*d2p1 - sp*d1p1, m2p2 = cp*d2p2 - sp*d1p2;
    float m1n0 = cn*d1n0 + sn*d2n0, m1n1 = cn*d1n1 + sn*d2n1, m1n2 = cn*d1n2 + sn*d2n2;
    float m2n0 = cn*d2n0 - sn*d1n0, m2n1 = cn*d2n1 - sn*d1n1, m2n2 = cn*d2n2 - sn*d1n2;
    float m1s0 = m1p0+m1n0, m1s1 = m1p1+m1n1, m1s2 = m1p2+m1n2;
    float m2s0 = m2p0+m2n0, m2s1 = m2p1+m2n1, m2s2 = m2p2+m2n2;
    float st0 = lp/l0p - 1.f;                                  // strain_p
    float st1 = ln/l0n - 1.f;                                  // strain_n
    float st2 =  0.5f*(kb0*m2s0 + kb1*m2s1 + kb2*m2s2);        // kappa1
    float st3 = -0.5f*(kb0*m1s0 + kb1*m1s1 + kb2*m1s2);        // kappa2
    float st4 = thn - thp;                                     // tau

    // ---- MLP forward: z2 accumulators (single 64-reg array, static indexing only) ----
    float acc[64];
    #pragma unroll
    for (int j = 0; j < 64; ++j) acc[j] = sB2[j];

    #pragma unroll 4
    for (int i = 0; i < 64; ++i) {
        float z1 = sB1[i] + st0*sW1[i] + st1*sW1[64+i] + st2*sW1[128+i]
                 + st3*sW1[192+i] + st4*sW1[256+i];
        float hi = tanh_fast(z1);
        const float4* w2r = reinterpret_cast<const float4*>(&sW2[i*64]);
        #pragma unroll
        for (int j4 = 0; j4 < 16; ++j4) {
            float4 w = w2r[j4];
            acc[4*j4+0] = fmaf(hi, w.x, acc[4*j4+0]);
            acc[4*j4+1] = fmaf(hi, w.y, acc[4*j4+1]);
            acc[4*j4+2] = fmaf(hi, w.z, acc[4*j4+2]);
            acc[4*j4+3] = fmaf(hi, w.w, acc[4*j4+3]);
        }
    }

    // h2 = tanh(z2); z3 = h2.W3 + b3 (4 partial sums to break the fma chain)
    float z3a = 0.f, z3b = 0.f, z3c = 0.f, z3d = 0.f;
    #pragma unroll
    for (int j = 0; j < 64; j += 4) {
        float h0 = tanh_fast(acc[j+0]); acc[j+0] = h0;
        float h1v = tanh_fast(acc[j+1]); acc[j+1] = h1v;
        float h2v = tanh_fast(acc[j+2]); acc[j+2] = h2v;
        float h3 = tanh_fast(acc[j+3]); acc[j+3] = h3;
        z3a = fmaf(h0, sW3[j+0], z3a);
        z3b = fmaf(h1v, sW3[j+1], z3b);
        z3c = fmaf(h2v, sW3[j+2], z3c);
        z3d = fmaf(h3, sW3[j+3], z3d);
    }
    float z3 = (z3a + z3b) + (z3c + z3d) + b3[0];
    float sig = 1.f / (1.f + __expf(-z3));      // dE/dz3 (softplus')

    // gz2 = sig * W3 * (1 - h2^2)  (overwrite acc in place)
    #pragma unroll
    for (int j = 0; j < 64; ++j) {
        float h2 = acc[j];
        acc[j] = sig * sW3[j] * (1.f - h2*h2);
    }

    // ---- MLP backward: gs = W1 @ ((W2 @ gz2) * (1-h1^2)) ----
    float gs0 = 0.f, gs1 = 0.f, gs2 = 0.f, gs3 = 0.f, gs4 = 0.f;
    #pragma unroll 4
    for (int i = 0; i < 64; ++i) {
        const float4* w2r = reinterpret_cast<const float4*>(&sW2[i*64]);
        float g0 = 0.f, g1 = 0.f, g2 = 0.f, g3 = 0.f;
        #pragma unroll
        for (int j4 = 0; j4 < 16; ++j4) {
            float4 w = w2r[j4];
            g0 = fmaf(w.x, acc[4*j4+0], g0);
            g1 = fmaf(w.y, acc[4*j4+1], g1);
            g2 = fmaf(w.z, acc[4*j4+2], g2);
            g3 = fmaf(w.w, acc[4*j4+3], g3);
        }
        float gh1 = (g0 + g1) + (g2 + g3);
        // recompute h1_i (avoids a second 64-reg array)
        float z1 = sB1[i] + st0*sW1[i] + st1*sW1[64+i] + st2*sW1[128+i]
                 + st3*sW1[192+i] + st4*sW1[256+i];
        float h1 = tanh_fast(z1);
        float gz1 = gh1 * (1.f - h1*h1);
        gs0 = fmaf(sW1[i],     gz1, gs0);
        gs1 = fmaf(sW1[64+i],  gz1, gs1);
        gs2 = fmaf(sW1[128+i], gz1, gs2);
        gs3 = fmaf(sW1[192+i], gz1, gs3);
        gs4 = fmaf(sW1[256+i], gz1, gs4);
    }

    // ---- reverse through strain geometry (adjoints of energy wrt q_s) ----
    float gkb0 = 0.5f*(gs2*m2s0 - gs3*m1s0);
    float gkb1 = 0.5f*(gs2*m2s1 - gs3*m1s1);
    float gkb2 = 0.5f*(gs2*m2s2 - gs3*m1s2);

    float kbm1p = kb0*m1p0 + kb1*m1p1 + kb2*m1p2;
    float kbm2p = kb0*m2p0 + kb1*m2p1 + kb2*m2p2;
    float kbm1n = kb0*m1n0 + kb1*m1n1 + kb2*m1n2;
    float kbm2n = kb0*m2n0 + kb1*m2n1 + kb2*m2n2;
    float gthp = -gs4 - 0.5f*(gs2*kbm1p + gs3*kbm2p);   // dm2p/dthp=-m1p, dm1p/dthp=m2p
    float gthn =  gs4 - 0.5f*(gs2*kbm1n + gs3*kbm2n);

    float gcr0 = 2.f*gkb0*idenom, gcr1 = 2.f*gkb1*idenom, gcr2 = 2.f*gkb2*idenom;
    float gc = -(gkb0*kb0 + gkb1*kb1 + gkb2*kb2)*idenom;

    float gtp0 = tn1*gcr2 - tn2*gcr1 + gc*tn0;   // tn x gcr + gc*tn
    float gtp1 = tn2*gcr0 - tn0*gcr2 + gc*tn1;
    float gtp2 = tn0*gcr1 - tn1*gcr0 + gc*tn2;
    float gtn0 = gcr1*tp2 - gcr2*tp1 + gc*tp0;   // gcr x tp + gc*tp
    float gtn1 = gcr2*tp0 - gcr0*tp2 + gc*tp1;
    float gtn2 = gcr0*tp1 - gcr1*tp0 + gc*tp2;

    float gep0 = gtp0*ilp, gep1 = gtp1*ilp, gep2 = gtp2*ilp;
    float gilp = gtp0*ep0 + gtp1*ep1 + gtp2*ep2;
    float glp  = gs0/l0p - gilp*ilp*ilp;
    float tl   = glp/lp;
    gep0 = fmaf(tl, ep0, gep0); gep1 = fmaf(tl, ep1, gep1); gep2 = fmaf(tl, ep2, gep2);

    float gen0 = gtn0*iln, gen1 = gtn1*iln, gen2 = gtn2*iln;
    float giln = gtn0*en0 + gtn1*en1 + gtn2*en2;
    float gln  = gs1/l0n - giln*iln*iln;
    float ul   = gln/ln;
    gen0 = fmaf(ul, en0, gen0); gen1 = fmaf(ul, en1, gen1); gen2 = fmaf(ul, en2, gen2);

    // forces = -grad;  xi: -gep, xj: gep-gen, xk: gen  -> negate
    float fxi0 = gep0,       fxi1 = gep1,       fxi2 = gep2;
    float fxj0 = gen0-gep0,  fxj1 = gen1-gep1,  fxj2 = gen2-gep2;
    float fxk0 = -gen0,      fxk1 = -gen1,      fxk2 = -gen2;
    float fthp = -gthp, fthn = -gthn;

    // ---- scatter (divide by M diagonal; M=I here but read it anyway) ----
    float* oa = out + (size_t)b * (size_t)(2*ndof) + ndof;
    const size_t nd1 = (size_t)ndof + 1;
    int di = 3*ni, dj = 3*nj, dk = 3*nk, dp = nodal + iep, dn = nodal + ien;
    atomicAdd(oa + di + 0, fxi0 * __builtin_amdgcn_rcpf(Mff[(size_t)(di+0)*nd1]));
    atomicAdd(oa + di + 1, fxi1 * __builtin_amdgcn_rcpf(Mff[(size_t)(di+1)*nd1]));
    atomicAdd(oa + di + 2, fxi2 * __builtin_amdgcn_rcpf(Mff[(size_t)(di+2)*nd1]));
    atomicAdd(oa + dj + 0, fxj0 * __builtin_amdgcn_rcpf(Mff[(size_t)(dj+0)*nd1]));
    atomicAdd(oa + dj + 1, fxj1 * __builtin_amdgcn_rcpf(Mff[(size_t)(dj+1)*nd1]));
    atomicAdd(oa + dj + 2, fxj2 * __builtin_amdgcn_rcpf(Mff[(size_t)(dj+2)*nd1]));
    atomicAdd(oa + dk + 0, fxk0 * __builtin_amdgcn_rcpf(Mff[(size_t)(dk+0)*nd1]));
    atomicAdd(oa + dk + 1, fxk1 * __builtin_amdgcn_rcpf(Mff[(size_t)(dk+1)*nd1]));
    atomicAdd(oa + dk + 2, fxk2 * __builtin_amdgcn_rcpf(Mff[(size_t)(dk+2)*nd1]));
    atomicAdd(oa + dp,     fthp * __builtin_amdgcn_rcpf(Mff[(size_t)dp*nd1]));
    atomicAdd(oa + dn,     fthn * __builtin_amdgcn_rcpf(Mff[(size_t)dn*nd1]));
}

extern "C" void kernel_launch(void* const* d_in, const int* in_sizes, int n_in,
                              void* d_out, int out_size, void* d_ws, size_t ws_size,
                              hipStream_t stream) {
    const float* x    = (const float*)d_in[1];
    const float* W1   = (const float*)d_in[2];
    const float* b1   = (const float*)d_in[3];
    const float* W2   = (const float*)d_in[4];
    const float* b2   = (const float*)d_in[5];
    const float* W3   = (const float*)d_in[6];
    const float* b3   = (const float*)d_in[7];
    const float* C    = (const float*)d_in[8];
    const float* Mff  = (const float*)d_in[9];
    const float* fext = (const float*)d_in[10];
    const float* l0e  = (const float*)d_in[11];
    const float* d1i  = (const float*)d_in[12];
    const float* d2i  = (const float*)d_in[13];
    const int* springs = (const int*)d_in[14];
    float* out = (float*)d_out;

    int ndof  = in_sizes[10];          // f_ext
    int E     = in_sizes[11];          // l0_edges
    int S     = in_sizes[14] / 5;      // springs rows
    int nodal = ndof - E;              // 3*N
    int B     = in_sizes[1] / (2 * ndof);

    int totInit = B * ndof;
    k_init<<<(totInit + 255) / 256, 256, 0, stream>>>(x, C, Mff, fext, out, B, ndof);

    int totF = B * S;
    k_force<<<(totF + 255) / 256, 256, 0, stream>>>(x, W1, b1, W2, b2, W3, b3, Mff,
                                                    l0e, d1i, d2i, springs, out,
                                                    B, S, ndof, nodal);
}

// Round 2
// 201.130 us; speedup vs baseline: 2.3500x; 2.3500x over previous
//
#include <hip/hip_runtime.h>

#define EPSF 1e-12f

__device__ __forceinline__ float rcpf(float x) { return __builtin_amdgcn_rcpf(x); }

// tanh(x) = 1 - 2/(1+e^{2x}); saturates correctly at +-inf without clamping
__device__ __forceinline__ float tanh_fast(float x) {
    float e = __expf(2.f * x);
    return 1.f - 2.f * rcpf(e + 1.f);
}

// One thread per (batch, spring). Weights read with wave-uniform addresses
// (loop counters only) -> compiler scalarizes to s_load + v_fmac v,s,v:
// no LDS, no per-lane weight traffic.
// USE_WS=1: write 11 force components to fs[b][slot][s] (coalesced, no atomics)
// USE_WS=0: fallback - atomicAdd into out accel half (round-1 proven path)
template<int USE_WS>
__global__ __launch_bounds__(256) void k_force(
    const float* __restrict__ x,
    const float* __restrict__ W1, const float* __restrict__ b1,
    const float* __restrict__ W2, const float* __restrict__ b2,
    const float* __restrict__ W3, const float* __restrict__ b3,
    const float* __restrict__ Mff,
    const float* __restrict__ l0e,
    const float* __restrict__ d1i, const float* __restrict__ d2i,
    const int* __restrict__ springs,
    float* __restrict__ dst,            // fs (USE_WS=1) or out (USE_WS=0)
    int B, int S, int ndof, int nodal)
{
    int tid = blockIdx.x * 256 + threadIdx.x;
    if (tid >= B * S) return;
    int b = tid / S;
    int s = tid - b * S;

    const int* spr = springs + 5 * s;
    int ni = spr[0], nj = spr[1], nk = spr[2], iep = spr[3], ien = spr[4];

    const float* q = x + (size_t)b * (size_t)(2 * ndof);
    float xi0 = q[3*ni+0], xi1 = q[3*ni+1], xi2 = q[3*ni+2];
    float xj0 = q[3*nj+0], xj1 = q[3*nj+1], xj2 = q[3*nj+2];
    float xk0 = q[3*nk+0], xk1 = q[3*nk+1], xk2 = q[3*nk+2];
    float thp = q[nodal + iep], thn = q[nodal + ien];
    float l0p = l0e[iep], l0n = l0e[ien];
    float d1p0 = d1i[3*iep+0], d1p1 = d1i[3*iep+1], d1p2 = d1i[3*iep+2];
    float d2p0 = d2i[3*iep+0], d2p1 = d2i[3*iep+1], d2p2 = d2i[3*iep+2];
    float d1n0 = d1i[3*ien+0], d1n1 = d1i[3*ien+1], d1n2 = d1i[3*ien+2];
    float d2n0 = d2i[3*ien+0], d2n1 = d2i[3*ien+1], d2n2 = d2i[3*ien+2];

    // ---- forward strains (matches reference incl. eps placement) ----
    float ep0 = xj0-xi0, ep1 = xj1-xi1, ep2 = xj2-xi2;
    float en0 = xk0-xj0, en1 = xk1-xj1, en2 = xk2-xj2;
    float lp = sqrtf(ep0*ep0 + ep1*ep1 + ep2*ep2);
    float ln = sqrtf(en0*en0 + en1*en1 + en2*en2);
    float ilp = rcpf(lp + EPSF), iln = rcpf(ln + EPSF);
    float tp0 = ep0*ilp, tp1 = ep1*ilp, tp2 = ep2*ilp;
    float tn0 = en0*iln, tn1 = en1*iln, tn2 = en2*iln;
    float cdot = tp0*tn0 + tp1*tn1 + tp2*tn2;
    float idenom = rcpf(1.f + cdot + EPSF);
    float cr0 = tp1*tn2 - tp2*tn1;
    float cr1 = tp2*tn0 - tp0*tn2;
    float cr2 = tp0*tn1 - tp1*tn0;
    float kb0 = 2.f*cr0*idenom, kb1 = 2.f*cr1*idenom, kb2 = 2.f*cr2*idenom;
    float cp, sp; __sincosf(thp, &sp, &cp);
    float cn, sn; __sincosf(thn, &sn, &cn);
    float m1p0 = cp*d1p0 + sp*d2p0, m1p1 = cp*d1p1 + sp*d2p1, m1p2 = cp*d1p2 + sp*d2p2;
    float m2p0 = cp*d2p0 - sp*d1p0, m2p1 = cp*d2p1 - sp*d1p1, m2p2 = cp*d2p2 - sp*d1p2;
    float m1n0 = cn*d1n0 + sn*d2n0, m1n1 = cn*d1n1 + sn*d2n1, m1n2 = cn*d1n2 + sn*d2n2;
    float m2n0 = cn*d2n0 - sn*d1n0, m2n1 = cn*d2n1 - sn*d1n1, m2n2 = cn*d2n2 - sn*d1n2;
    float m1s0 = m1p0+m1n0, m1s1 = m1p1+m1n1, m1s2 = m1p2+m1n2;
    float m2s0 = m2p0+m2n0, m2s1 = m2p1+m2n1, m2s2 = m2p2+m2n2;
    float il0p = rcpf(l0p), il0n = rcpf(l0n);
    float st0 = lp*il0p - 1.f;                                 // strain_p
    float st1 = ln*il0n - 1.f;                                 // strain_n
    float st2 =  0.5f*(kb0*m2s0 + kb1*m2s1 + kb2*m2s2);        // kappa1
    float st3 = -0.5f*(kb0*m1s0 + kb1*m1s1 + kb2*m1s2);        // kappa2
    float st4 = thn - thp;                                     // tau

    // ---- MLP forward: z2 accumulators (static indexing only) ----
    const float4* W2v = reinterpret_cast<const float4*>(W2);   // [64][16] float4, uniform
    float acc[64];
    #pragma unroll
    for (int j = 0; j < 64; ++j) acc[j] = b2[j];

    #pragma unroll 4
    for (int i = 0; i < 64; ++i) {
        float z1 = b1[i] + st0*W1[i] + st1*W1[64+i] + st2*W1[128+i]
                 + st3*W1[192+i] + st4*W1[256+i];
        float hi = tanh_fast(z1);
        #pragma unroll
        for (int j4 = 0; j4 < 16; ++j4) {
            float4 w = W2v[i*16 + j4];                         // uniform -> s_load_dwordx4
            acc[4*j4+0] = fmaf(hi, w.x, acc[4*j4+0]);
            acc[4*j4+1] = fmaf(hi, w.y, acc[4*j4+1]);
            acc[4*j4+2] = fmaf(hi, w.z, acc[4*j4+2]);
            acc[4*j4+3] = fmaf(hi, w.w, acc[4*j4+3]);
        }
    }

    // h2 = tanh(z2); z3 = h2.W3 + b3
    float z3a = 0.f, z3b = 0.f, z3c = 0.f, z3d = 0.f;
    #pragma unroll
    for (int j = 0; j < 64; j += 4) {
        float h0 = tanh_fast(acc[j+0]); acc[j+0] = h0;
        float h1v = tanh_fast(acc[j+1]); acc[j+1] = h1v;
        float h2v = tanh_fast(acc[j+2]); acc[j+2] = h2v;
        float h3 = tanh_fast(acc[j+3]); acc[j+3] = h3;
        z3a = fmaf(h0,  W3[j+0], z3a);
        z3b = fmaf(h1v, W3[j+1], z3b);
        z3c = fmaf(h2v, W3[j+2], z3c);
        z3d = fmaf(h3,  W3[j+3], z3d);
    }
    float z3 = (z3a + z3b) + (z3c + z3d) + b3[0];
    float sig = rcpf(1.f + __expf(-z3));        // softplus'

    // gz2 = sig * W3 * (1 - h2^2)
    #pragma unroll
    for (int j = 0; j < 64; ++j) {
        float h2 = acc[j];
        acc[j] = sig * W3[j] * (1.f - h2*h2);
    }

    // ---- MLP backward: gs = W1 @ ((W2 @ gz2) * (1-h1^2)) ----
    float gs0 = 0.f, gs1 = 0.f, gs2 = 0.f, gs3 = 0.f, gs4 = 0.f;
    #pragma unroll 4
    for (int i = 0; i < 64; ++i) {
        float g0 = 0.f, g1 = 0.f, g2 = 0.f, g3 = 0.f;
        #pragma unroll
        for (int j4 = 0; j4 < 16; ++j4) {
            float4 w = W2v[i*16 + j4];                         // uniform -> s_load_dwordx4
            g0 = fmaf(w.x, acc[4*j4+0], g0);
            g1 = fmaf(w.y, acc[4*j4+1], g1);
            g2 = fmaf(w.z, acc[4*j4+2], g2);
            g3 = fmaf(w.w, acc[4*j4+3], g3);
        }
        float gh1 = (g0 + g1) + (g2 + g3);
        float z1 = b1[i] + st0*W1[i] + st1*W1[64+i] + st2*W1[128+i]
                 + st3*W1[192+i] + st4*W1[256+i];
        float h1 = tanh_fast(z1);
        float gz1 = gh1 * (1.f - h1*h1);
        gs0 = fmaf(W1[i],     gz1, gs0);
        gs1 = fmaf(W1[64+i],  gz1, gs1);
        gs2 = fmaf(W1[128+i], gz1, gs2);
        gs3 = fmaf(W1[192+i], gz1, gs3);
        gs4 = fmaf(W1[256+i], gz1, gs4);
    }

    // ---- reverse through strain geometry ----
    float gkb0 = 0.5f*(gs2*m2s0 - gs3*m1s0);
    float gkb1 = 0.5f*(gs2*m2s1 - gs3*m1s1);
    float gkb2 = 0.5f*(gs2*m2s2 - gs3*m1s2);

    float kbm1p = kb0*m1p0 + kb1*m1p1 + kb2*m1p2;
    float kbm2p = kb0*m2p0 + kb1*m2p1 + kb2*m2p2;
    float kbm1n = kb0*m1n0 + kb1*m1n1 + kb2*m1n2;
    float kbm2n = kb0*m2n0 + kb1*m2n1 + kb2*m2n2;
    float gthp = -gs4 - 0.5f*(gs2*kbm1p + gs3*kbm2p);
    float gthn =  gs4 - 0.5f*(gs2*kbm1n + gs3*kbm2n);

    float gcr0 = 2.f*gkb0*idenom, gcr1 = 2.f*gkb1*idenom, gcr2 = 2.f*gkb2*idenom;
    float gc = -(gkb0*kb0 + gkb1*kb1 + gkb2*kb2)*idenom;

    float gtp0 = tn1*gcr2 - tn2*gcr1 + gc*tn0;
    float gtp1 = tn2*gcr0 - tn0*gcr2 + gc*tn1;
    float gtp2 = tn0*gcr1 - tn1*gcr0 + gc*tn2;
    float gtn0 = gcr1*tp2 - gcr2*tp1 + gc*tp0;
    float gtn1 = gcr2*tp0 - gcr0*tp2 + gc*tp1;
    float gtn2 = gcr0*tp1 - gcr1*tp0 + gc*tp2;

    float gep0 = gtp0*ilp, gep1 = gtp1*ilp, gep2 = gtp2*ilp;
    float gilp = gtp0*ep0 + gtp1*ep1 + gtp2*ep2;
    float glp  = gs0*il0p - gilp*ilp*ilp;
    float tl   = glp*rcpf(lp);
    gep0 = fmaf(tl, ep0, gep0); gep1 = fmaf(tl, ep1, gep1); gep2 = fmaf(tl, ep2, gep2);

    float gen0 = gtn0*iln, gen1 = gtn1*iln, gen2 = gtn2*iln;
    float giln = gtn0*en0 + gtn1*en1 + gtn2*en2;
    float gln  = gs1*il0n - giln*iln*iln;
    float ul   = gln*rcpf(ln);
    gen0 = fmaf(ul, en0, gen0); gen1 = fmaf(ul, en1, gen1); gen2 = fmaf(ul, en2, gen2);

    // forces = -grad
    float fxi0 = gep0,       fxi1 = gep1,       fxi2 = gep2;
    float fxj0 = gen0-gep0,  fxj1 = gen1-gep1,  fxj2 = gen2-gep2;
    float fxk0 = -gen0,      fxk1 = -gen1,      fxk2 = -gen2;
    float fthp = -gthp, fthn = -gthn;

    if (USE_WS) {
        // coalesced slot-major stores, no atomics
        float* fsb = dst + (size_t)b * (size_t)(11 * S) + s;
        fsb[0*S] = fxi0; fsb[1*S] = fxi1; fsb[2*S] = fxi2;
        fsb[3*S] = fxj0; fsb[4*S] = fxj1; fsb[5*S] = fxj2;
        fsb[6*S] = fxk0; fsb[7*S] = fxk1; fsb[8*S] = fxk2;
        fsb[9*S] = fthp; fsb[10*S] = fthn;
    } else {
        float* oa = dst + (size_t)b * (size_t)(2*ndof) + ndof;
        const size_t nd1 = (size_t)ndof + 1;
        int di = 3*ni, dj = 3*nj, dk = 3*nk, dp = nodal + iep, dn = nodal + ien;
        atomicAdd(oa + di + 0, fxi0 * rcpf(Mff[(size_t)(di+0)*nd1]));
        atomicAdd(oa + di + 1, fxi1 * rcpf(Mff[(size_t)(di+1)*nd1]));
        atomicAdd(oa + di + 2, fxi2 * rcpf(Mff[(size_t)(di+2)*nd1]));
        atomicAdd(oa + dj + 0, fxj0 * rcpf(Mff[(size_t)(dj+0)*nd1]));
        atomicAdd(oa + dj + 1, fxj1 * rcpf(Mff[(size_t)(dj+1)*nd1]));
        atomicAdd(oa + dj + 2, fxj2 * rcpf(Mff[(size_t)(dj+2)*nd1]));
        atomicAdd(oa + dk + 0, fxk0 * rcpf(Mff[(size_t)(dk+0)*nd1]));
        atomicAdd(oa + dk + 1, fxk1 * rcpf(Mff[(size_t)(dk+1)*nd1]));
        atomicAdd(oa + dk + 2, fxk2 * rcpf(Mff[(size_t)(dk+2)*nd1]));
        atomicAdd(oa + dp,     fthp * rcpf(Mff[(size_t)dp*nd1]));
        atomicAdd(oa + dn,     fthn * rcpf(Mff[(size_t)dn*nd1]));
    }
}

// out[:, :ndof] = v ; out[:, ndof:] = (f_ext - Cdd*v + gather(fs)) / Mdd
// GATHER=0: init only (atomic fallback accumulates afterwards)
template<int GATHER>
__global__ void k_out(const float* __restrict__ x, const float* __restrict__ C,
                      const float* __restrict__ Mff, const float* __restrict__ fext,
                      const float* __restrict__ fs, float* __restrict__ out,
                      int B, int ndof, int nodal, int S) {
    int idx = blockIdx.x * blockDim.x + threadIdx.x;
    if (idx >= B * ndof) return;
    int b = idx / ndof;
    int d = idx - b * ndof;
    size_t row = (size_t)b * (size_t)(2 * ndof);
    const size_t nd1 = (size_t)ndof + 1;
    float vd = x[row + ndof + d];
    out[row + d] = vd;
    float acc = fext[d] - C[(size_t)d * nd1] * vd;
    if (GATHER) {
        const float* fsb = fs + (size_t)b * (size_t)(11 * S);
        if (d < nodal) {
            int n = d / 3, c = d - 3 * n;
            if (n < S)            acc += fsb[(size_t)(0 + c) * S + n];
            if (n >= 1 && n <= S) acc += fsb[(size_t)(3 + c) * S + n - 1];
            if (n >= 2)           acc += fsb[(size_t)(6 + c) * S + n - 2];
        } else {
            int e = d - nodal;
            if (e < S)  acc += fsb[(size_t)9 * S + e];
            if (e >= 1) acc += fsb[(size_t)10 * S + e - 1];
        }
    }
    out[row + ndof + d] = acc * rcpf(Mff[(size_t)d * nd1]);
}

extern "C" void kernel_launch(void* const* d_in, const int* in_sizes, int n_in,
                              void* d_out, int out_size, void* d_ws, size_t ws_size,
                              hipStream_t stream) {
    const float* x    = (const float*)d_in[1];
    const float* W1   = (const float*)d_in[2];
    const float* b1   = (const float*)d_in[3];
    const float* W2   = (const float*)d_in[4];
    const float* b2   = (const float*)d_in[5];
    const float* W3   = (const float*)d_in[6];
    const float* b3   = (const float*)d_in[7];
    const float* C    = (const float*)d_in[8];
    const float* Mff  = (const float*)d_in[9];
    const float* fext = (const float*)d_in[10];
    const float* l0e  = (const float*)d_in[11];
    const float* d1i  = (const float*)d_in[12];
    const float* d2i  = (const float*)d_in[13];
    const int* springs = (const int*)d_in[14];
    float* out = (float*)d_out;

    int ndof  = in_sizes[10];
    int E     = in_sizes[11];
    int S     = in_sizes[14] / 5;
    int nodal = ndof - E;
    int B     = in_sizes[1] / (2 * ndof);

    int totF = B * S;
    int totO = B * ndof;
    size_t ws_need = (size_t)B * (size_t)(11 * S) * sizeof(float);

    if (d_ws && ws_size >= ws_need) {
        float* fs = (float*)d_ws;
        k_force<1><<<(totF + 255) / 256, 256, 0, stream>>>(x, W1, b1, W2, b2, W3, b3, Mff,
                                                           l0e, d1i, d2i, springs, fs,
                                                           B, S, ndof, nodal);
        k_out<1><<<(totO + 255) / 256, 256, 0, stream>>>(x, C, Mff, fext, fs, out,
                                                         B, ndof, nodal, S);
    } else {
        k_out<0><<<(totO + 255) / 256, 256, 0, stream>>>(x, C, Mff, fext, nullptr, out,
                                                         B, ndof, nodal, S);
        k_force<0><<<(totF + 255) / 256, 256, 0, stream>>>(x, W1, b1, W2, b2, W3, b3, Mff,
                                                           l0e, d1i, d2i, springs, out,
                                                           B, S, ndof, nodal);
    }
}

// Round 4
// 154.679 us; speedup vs baseline: 3.0557x; 1.3003x over previous
//
#include <hip/hip_runtime.h>

#define EPSF 1e-12f

typedef __attribute__((ext_vector_type(8))) short short8;
typedef __attribute__((ext_vector_type(4))) float f32x4;

__device__ __forceinline__ float rcpf(float x) { return __builtin_amdgcn_rcpf(x); }

// tanh(x) = 1 - 2/(1+e^{2x}); saturates correctly without clamping
__device__ __forceinline__ float tanh_fast(float x) {
    float e = __expf(2.f * x);
    return 1.f - 2.f * rcpf(e + 1.f);
}

// Slot convention lambda: packed column p = kc*32 + g4*8 + j holds logical k =
// kc*32 + 16*(j>>2) + 4*g4 + (j&3). pcol maps logical k -> packed column.
// Both MFMA operands use the same lambda => result correct for ANY hw k-map.
__device__ __forceinline__ int pcol(int v) {
    return (v >> 5) * 32 + ((v >> 2) & 3) * 8 + (((v >> 4) & 1) << 2) + (v & 3);
}

union U8 { short8 s; unsigned int u[4]; };

__device__ __forceinline__ unsigned int hi2(float x, float y) {
    // (bf16_trunc(y) << 16) | bf16_trunc(x)
    return __builtin_amdgcn_perm(__float_as_uint(y), __float_as_uint(x), 0x07060302u);
}
__device__ __forceinline__ float resid(float x) {
    return x - __uint_as_float(__float_as_uint(x) & 0xFFFF0000u);
}
// elements in slot order: a[0..3] -> slots 0..3, b[0..3] -> slots 4..7
__device__ __forceinline__ void pack8v(f32x4 a, f32x4 b, short8& hs, short8& ls) {
    U8 H, L;
    H.u[0] = hi2(a[0], a[1]); H.u[1] = hi2(a[2], a[3]);
    H.u[2] = hi2(b[0], b[1]); H.u[3] = hi2(b[2], b[3]);
    L.u[0] = hi2(resid(a[0]), resid(a[1])); L.u[1] = hi2(resid(a[2]), resid(a[3]));
    L.u[2] = hi2(resid(b[0]), resid(b[1])); L.u[3] = hi2(resid(b[2]), resid(b[3]));
    hs = H.s; ls = L.s;
}

struct Geom {
    float st0, st1, st2, st3, st4;
    float ep0,ep1,ep2, en0,en1,en2;
    float lp, ln, ilp, iln, il0p, il0n, idenom;
    float tp0,tp1,tp2, tn0,tn1,tn2;
    float kb0,kb1,kb2;
    float m1p0,m1p1,m1p2, m2p0,m2p1,m2p2;
    float m1n0,m1n1,m1n2, m2n0,m2n1,m2n2;
    float m1s0,m1s1,m1s2, m2s0,m2s1,m2s2;
};

__device__ __forceinline__ Geom compute_geom(
        const float* __restrict__ q, const int* __restrict__ spr,
        const float* __restrict__ l0e, const float* __restrict__ d1i,
        const float* __restrict__ d2i, int nodal) {
    Geom G;
    int ni = spr[0], nj = spr[1], nk = spr[2], iep = spr[3], ien = spr[4];
    float xi0 = q[3*ni+0], xi1 = q[3*ni+1], xi2 = q[3*ni+2];
    float xj0 = q[3*nj+0], xj1 = q[3*nj+1], xj2 = q[3*nj+2];
    float xk0 = q[3*nk+0], xk1 = q[3*nk+1], xk2 = q[3*nk+2];
    float thp = q[nodal + iep], thn = q[nodal + ien];
    float l0p = l0e[iep], l0n = l0e[ien];
    float d1p0 = d1i[3*iep+0], d1p1 = d1i[3*iep+1], d1p2 = d1i[3*iep+2];
    float d2p0 = d2i[3*iep+0], d2p1 = d2i[3*iep+1], d2p2 = d2i[3*iep+2];
    float d1n0 = d1i[3*ien+0], d1n1 = d1i[3*ien+1], d1n2 = d1i[3*ien+2];
    float d2n0 = d2i[3*ien+0], d2n1 = d2i[3*ien+1], d2n2 = d2i[3*ien+2];

    G.ep0 = xj0-xi0; G.ep1 = xj1-xi1; G.ep2 = xj2-xi2;
    G.en0 = xk0-xj0; G.en1 = xk1-xj1; G.en2 = xk2-xj2;
    G.lp = sqrtf(G.ep0*G.ep0 + G.ep1*G.ep1 + G.ep2*G.ep2);
    G.ln = sqrtf(G.en0*G.en0 + G.en1*G.en1 + G.en2*G.en2);
    G.ilp = rcpf(G.lp + EPSF); G.iln = rcpf(G.ln + EPSF);
    G.tp0 = G.ep0*G.ilp; G.tp1 = G.ep1*G.ilp; G.tp2 = G.ep2*G.ilp;
    G.tn0 = G.en0*G.iln; G.tn1 = G.en1*G.iln; G.tn2 = G.en2*G.iln;
    float cdot = G.tp0*G.tn0 + G.tp1*G.tn1 + G.tp2*G.tn2;
    G.idenom = rcpf(1.f + cdot + EPSF);
    float cr0 = G.tp1*G.tn2 - G.tp2*G.tn1;
    float cr1 = G.tp2*G.tn0 - G.tp0*G.tn2;
    float cr2 = G.tp0*G.tn1 - G.tp1*G.tn0;
    G.kb0 = 2.f*cr0*G.idenom; G.kb1 = 2.f*cr1*G.idenom; G.kb2 = 2.f*cr2*G.idenom;
    float cp, sp; __sincosf(thp, &sp, &cp);
    float cn, sn; __sincosf(thn, &sn, &cn);
    G.m1p0 = cp*d1p0 + sp*d2p0; G.m1p1 = cp*d1p1 + sp*d2p1; G.m1p2 = cp*d1p2 + sp*d2p2;
    G.m2p0 = cp*d2p0 - sp*d1p0; G.m2p1 = cp*d2p1 - sp*d1p1; G.m2p2 = cp*d2p2 - sp*d1p2;
    G.m1n0 = cn*d1n0 + sn*d2n0; G.m1n1 = cn*d1n1 + sn*d2n1; G.m1n2 = cn*d1n2 + sn*d2n2;
    G.m2n0 = cn*d2n0 - sn*d1n0; G.m2n1 = cn*d2n1 - sn*d1n1; G.m2n2 = cn*d2n2 - sn*d1n2;
    G.m1s0 = G.m1p0+G.m1n0; G.m1s1 = G.m1p1+G.m1n1; G.m1s2 = G.m1p2+G.m1n2;
    G.m2s0 = G.m2p0+G.m2n0; G.m2s1 = G.m2p1+G.m2n1; G.m2s2 = G.m2p2+G.m2n2;
    G.il0p = rcpf(l0p); G.il0n = rcpf(l0n);
    G.st0 = G.lp*G.il0p - 1.f;
    G.st1 = G.ln*G.il0n - 1.f;
    G.st2 =  0.5f*(G.kb0*G.m2s0 + G.kb1*G.m2s1 + G.kb2*G.m2s2);
    G.st3 = -0.5f*(G.kb0*G.m1s0 + G.kb1*G.m1s1 + G.kb2*G.m1s2);
    G.st4 = thn - thp;
    return G;
}

// geometry backward from gs[5]; writes 11 force slots (slot-major)
__device__ __forceinline__ void geom_backward_store(
        const Geom& G, const float gs0, const float gs1, const float gs2,
        const float gs3, const float gs4, float* __restrict__ fsb, int S) {
    float gkb0 = 0.5f*(gs2*G.m2s0 - gs3*G.m1s0);
    float gkb1 = 0.5f*(gs2*G.m2s1 - gs3*G.m1s1);
    float gkb2 = 0.5f*(gs2*G.m2s2 - gs3*G.m1s2);

    float kbm1p = G.kb0*G.m1p0 + G.kb1*G.m1p1 + G.kb2*G.m1p2;
    float kbm2p = G.kb0*G.m2p0 + G.kb1*G.m2p1 + G.kb2*G.m2p2;
    float kbm1n = G.kb0*G.m1n0 + G.kb1*G.m1n1 + G.kb2*G.m1n2;
    float kbm2n = G.kb0*G.m2n0 + G.kb1*G.m2n1 + G.kb2*G.m2n2;
    float gthp = -gs4 - 0.5f*(gs2*kbm1p + gs3*kbm2p);
    float gthn =  gs4 - 0.5f*(gs2*kbm1n + gs3*kbm2n);

    float gcr0 = 2.f*gkb0*G.idenom, gcr1 = 2.f*gkb1*G.idenom, gcr2 = 2.f*gkb2*G.idenom;
    float gc = -(gkb0*G.kb0 + gkb1*G.kb1 + gkb2*G.kb2)*G.idenom;

    float gtp0 = G.tn1*gcr2 - G.tn2*gcr1 + gc*G.tn0;
    float gtp1 = G.tn2*gcr0 - G.tn0*gcr2 + gc*G.tn1;
    float gtp2 = G.tn0*gcr1 - G.tn1*gcr0 + gc*G.tn2;
    float gtn0 = gcr1*G.tp2 - gcr2*G.tp1 + gc*G.tp0;
    float gtn1 = gcr2*G.tp0 - gcr0*G.tp2 + gc*G.tp1;
    float gtn2 = gcr0*G.tp1 - gcr1*G.tp0 + gc*G.tp2;

    float gep0 = gtp0*G.ilp, gep1 = gtp1*G.ilp, gep2 = gtp2*G.ilp;
    float gilp = gtp0*G.ep0 + gtp1*G.ep1 + gtp2*G.ep2;
    float glp  = gs0*G.il0p - gilp*G.ilp*G.ilp;
    float tl   = glp*rcpf(G.lp);
    gep0 = fmaf(tl, G.ep0, gep0); gep1 = fmaf(tl, G.ep1, gep1); gep2 = fmaf(tl, G.ep2, gep2);

    float gen0 = gtn0*G.iln, gen1 = gtn1*G.iln, gen2 = gtn2*G.iln;
    float giln = gtn0*G.en0 + gtn1*G.en1 + gtn2*G.en2;
    float gln  = gs1*G.il0n - giln*G.iln*G.iln;
    float ul   = gln*rcpf(G.ln);
    gen0 = fmaf(ul, G.en0, gen0); gen1 = fmaf(ul, G.en1, gen1); gen2 = fmaf(ul, G.en2, gen2);

    fsb[0*(size_t)S] = gep0;        fsb[1*(size_t)S] = gep1;        fsb[2*(size_t)S] = gep2;
    fsb[3*(size_t)S] = gen0-gep0;   fsb[4*(size_t)S] = gen1-gep1;   fsb[5*(size_t)S] = gen2-gep2;
    fsb[6*(size_t)S] = -gen0;       fsb[7*(size_t)S] = -gen1;       fsb[8*(size_t)S] = -gen2;
    fsb[9*(size_t)S] = -gthp;       fsb[10*(size_t)S] = -gthn;
}

#define MFMA_BF16 __builtin_amdgcn_mfma_f32_16x16x32_bf16

// ---------------- MFMA force kernel (wave = 16 springs) ----------------
// spring = lane&15; the 4 lane-groups g4 = lane>>4 co-own each spring.
// h1 is computed directly at i = 16*it + 4*g4 + r — simultaneously the
// B-operand slot positions (lambda) AND the verified C/D row positions.
// No dynamic LDS; backward B feeds straight from forward accumulators.
__global__ __launch_bounds__(256) void k_force_mfma(
    const float* __restrict__ x,
    const float* __restrict__ W1, const float* __restrict__ b1,
    const float* __restrict__ W2, const float* __restrict__ b2,
    const float* __restrict__ W3, const float* __restrict__ b3,
    const float* __restrict__ l0e,
    const float* __restrict__ d1i, const float* __restrict__ d2i,
    const int* __restrict__ springs,
    float* __restrict__ fs,
    int B, int S, int ndof, int nodal)
{
    __shared__ short sW2f[2][64*72];   // W2^T rows o, packed cols pcol(i)
    __shared__ short sW2b[2][64*72];   // W2   rows i, packed cols pcol(o)
    __shared__ float sWb1[5*64 + 64];  // W1 then b1

    const int t = threadIdx.x;
    #pragma unroll
    for (int e = 0; e < 16; ++e) {
        int L = t + 256*e;             // L = i*64 + o
        float w = W2[L];
        unsigned int u = __float_as_uint(w);
        short hsv = (short)(u >> 16);
        float lo = w - __uint_as_float(u & 0xFFFF0000u);
        short lsv = (short)(__float_as_uint(lo) >> 16);
        int i = L >> 6, o = L & 63;
        sW2f[0][o*72 + pcol(i)] = hsv; sW2f[1][o*72 + pcol(i)] = lsv;
        sW2b[0][i*72 + pcol(o)] = hsv; sW2b[1][i*72 + pcol(o)] = lsv;
    }
    for (int u2 = t; u2 < 320; u2 += 256) sWb1[u2] = W1[u2];
    if (t < 64) sWb1[320 + t] = b1[t];
    __syncthreads();

    const int lane = t & 63;
    const int wv = t >> 6;
    const int g4 = lane >> 4;          // lane-group 0..3
    const int m16 = lane & 15;         // spring within wave / MFMA row-col index

    int sp = (blockIdx.x * 4 + wv) * 16 + m16;
    const bool active = sp < B * S;
    int spc = active ? sp : 0;
    int b = spc / S;
    int s = spc - b * S;
    const int* spr = springs + 5 * s;
    const float* q = x + (size_t)b * (size_t)(2 * ndof);

    // ---- strains (geometry recomputed at the end to keep the middle lean) ----
    float st0, st1, st2, st3, st4;
    {
        Geom G = compute_geom(q, spr, l0e, d1i, d2i, nodal);
        st0 = G.st0; st1 = G.st1; st2 = G.st2; st3 = G.st3; st4 = G.st4;
    }

    // ---- h1 at i = 16*it + 4*g4 + r (16 tanh per lane) ----
    f32x4 h1v[4];
    #pragma unroll
    for (int it = 0; it < 4; ++it) {
        const int off = it*16 + g4*4;
        f32x4 b1f = *(const f32x4*)&sWb1[320 + off];
        f32x4 wa = *(const f32x4*)&sWb1[0*64 + off];
        f32x4 wb = *(const f32x4*)&sWb1[1*64 + off];
        f32x4 wc = *(const f32x4*)&sWb1[2*64 + off];
        f32x4 wd = *(const f32x4*)&sWb1[3*64 + off];
        f32x4 we = *(const f32x4*)&sWb1[4*64 + off];
        #pragma unroll
        for (int r = 0; r < 4; ++r) {
            float z1 = b1f[r] + st0*wa[r] + st1*wb[r] + st2*wc[r]
                     + st3*wd[r] + st4*we[r];
            h1v[it][r] = tanh_fast(z1);
        }
    }

    // ---- pack h1 into B fragments (slot order matches lambda by construction) ----
    short8 bh0, bl0, bh1, bl1;
    pack8v(h1v[0], h1v[1], bh0, bl0);   // kc=0: it 0,1
    pack8v(h1v[2], h1v[3], bh1, bl1);   // kc=1: it 2,3

    // ---- forward: z2^T[o][spring], acc[ot] covers o = ot*16 + 4*g4 + r ----
    f32x4 acc[4];
    #pragma unroll
    for (int ot = 0; ot < 4; ++ot)
        acc[ot] = *(const f32x4*)(b2 + ot*16 + g4*4);

    #pragma unroll
    for (int ot = 0; ot < 4; ++ot) {
        const int ro = (ot*16 + m16)*72 + g4*8;
        short8 ah0 = *(const short8*)&sW2f[0][ro];
        short8 al0 = *(const short8*)&sW2f[1][ro];
        short8 ah1 = *(const short8*)&sW2f[0][ro + 32];
        short8 al1 = *(const short8*)&sW2f[1][ro + 32];
        acc[ot] = MFMA_BF16(ah0, bh0, acc[ot], 0, 0, 0);
        acc[ot] = MFMA_BF16(ah0, bl0, acc[ot], 0, 0, 0);
        acc[ot] = MFMA_BF16(al0, bh0, acc[ot], 0, 0, 0);
        acc[ot] = MFMA_BF16(ah1, bh1, acc[ot], 0, 0, 0);
        acc[ot] = MFMA_BF16(ah1, bl1, acc[ot], 0, 0, 0);
        acc[ot] = MFMA_BF16(al1, bh1, acc[ot], 0, 0, 0);
    }

    // ---- middle: h2 = tanh(z2); z3 = h2.W3 (+2 shfl); sig; gz2 in place ----
    f32x4 w3v[4];
    #pragma unroll
    for (int ot = 0; ot < 4; ++ot)
        w3v[ot] = *(const f32x4*)(W3 + ot*16 + g4*4);

    float z3 = 0.f;
    #pragma unroll
    for (int ot = 0; ot < 4; ++ot)
        #pragma unroll
        for (int r = 0; r < 4; ++r) {
            float h2 = tanh_fast(acc[ot][r]);
            acc[ot][r] = h2;
            z3 = fmaf(h2, w3v[ot][r], z3);
        }
    z3 += __shfl_xor(z3, 16, 64);
    z3 += __shfl_xor(z3, 32, 64);
    z3 += b3[0];
    float sig = rcpf(1.f + __expf(-z3));       // softplus'

    #pragma unroll
    for (int ot = 0; ot < 4; ++ot)
        #pragma unroll
        for (int r = 0; r < 4; ++r) {
            float h2 = acc[ot][r];
            acc[ot][r] = sig * w3v[ot][r] * (1.f - h2*h2);
        }

    // ---- backward: g[i][spring] = W2 @ gz2 ; B feeds directly from acc ----
    pack8v(acc[0], acc[1], bh0, bl0);   // kc=0: o-tiles 0,1
    pack8v(acc[2], acc[3], bh1, bl1);   // kc=1: o-tiles 2,3

    f32x4 gg[4];
    #pragma unroll
    for (int it = 0; it < 4; ++it) gg[it] = (f32x4){0.f, 0.f, 0.f, 0.f};

    #pragma unroll
    for (int it = 0; it < 4; ++it) {
        const int ro = (it*16 + m16)*72 + g4*8;
        short8 ah0 = *(const short8*)&sW2b[0][ro];
        short8 al0 = *(const short8*)&sW2b[1][ro];
        short8 ah1 = *(const short8*)&sW2b[0][ro + 32];
        short8 al1 = *(const short8*)&sW2b[1][ro + 32];
        gg[it] = MFMA_BF16(ah0, bh0, gg[it], 0, 0, 0);
        gg[it] = MFMA_BF16(ah0, bl0, gg[it], 0, 0, 0);
        gg[it] = MFMA_BF16(al0, bh0, gg[it], 0, 0, 0);
        gg[it] = MFMA_BF16(ah1, bh1, gg[it], 0, 0, 0);
        gg[it] = MFMA_BF16(ah1, bl1, gg[it], 0, 0, 0);
        gg[it] = MFMA_BF16(al1, bh1, gg[it], 0, 0, 0);
    }

    // ---- gz1 = g*(1-h1^2) (h1 already at C positions); gs partials; reduce ----
    float p0 = 0.f, p1 = 0.f, p2 = 0.f, p3 = 0.f, p4 = 0.f;
    #pragma unroll
    for (int it = 0; it < 4; ++it) {
        const int off = it*16 + g4*4;
        f32x4 wa = *(const f32x4*)&sWb1[0*64 + off];
        f32x4 wb = *(const f32x4*)&sWb1[1*64 + off];
        f32x4 wc = *(const f32x4*)&sWb1[2*64 + off];
        f32x4 wd = *(const f32x4*)&sWb1[3*64 + off];
        f32x4 we = *(const f32x4*)&sWb1[4*64 + off];
        #pragma unroll
        for (int r = 0; r < 4; ++r) {
            float hv = h1v[it][r];
            float gz1 = gg[it][r] * (1.f - hv*hv);
            p0 = fmaf(gz1, wa[r], p0);
            p1 = fmaf(gz1, wb[r], p1);
            p2 = fmaf(gz1, wc[r], p2);
            p3 = fmaf(gz1, wd[r], p3);
            p4 = fmaf(gz1, we[r], p4);
        }
    }
    p0 += __shfl_xor(p0, 16, 64); p0 += __shfl_xor(p0, 32, 64);
    p1 += __shfl_xor(p1, 16, 64); p1 += __shfl_xor(p1, 32, 64);
    p2 += __shfl_xor(p2, 16, 64); p2 += __shfl_xor(p2, 32, 64);
    p3 += __shfl_xor(p3, 16, 64); p3 += __shfl_xor(p3, 32, 64);
    p4 += __shfl_xor(p4, 16, 64); p4 += __shfl_xor(p4, 32, 64);

    // ---- geometry backward + store (one lane-group per spring) ----
    if (active && g4 == 0) {
        Geom G = compute_geom(q, spr, l0e, d1i, d2i, nodal);
        float* fsb = fs + (size_t)b * (size_t)(11 * S) + s;
        geom_backward_store(G, p0, p1, p2, p3, p4, fsb, S);
    }
}

// ---------------- fallback: scalar per-thread kernel with atomics ----------------
__global__ __launch_bounds__(256) void k_force_scalar(
    const float* __restrict__ x,
    const float* __restrict__ W1, const float* __restrict__ b1,
    const float* __restrict__ W2, const float* __restrict__ b2,
    const float* __restrict__ W3, const float* __restrict__ b3,
    const float* __restrict__ Mff,
    const float* __restrict__ l0e,
    const float* __restrict__ d1i, const float* __restrict__ d2i,
    const int* __restrict__ springs,
    float* __restrict__ out,
    int B, int S, int ndof, int nodal)
{
    int tid = blockIdx.x * 256 + threadIdx.x;
    if (tid >= B * S) return;
    int b = tid / S;
    int s = tid - b * S;
    const int* spr = springs + 5 * s;
    const float* q = x + (size_t)b * (size_t)(2 * ndof);
    Geom G = compute_geom(q, spr, l0e, d1i, d2i, nodal);
    float st0 = G.st0, st1 = G.st1, st2 = G.st2, st3 = G.st3, st4 = G.st4;

    const float4* W2v = reinterpret_cast<const float4*>(W2);
    float accv[64];
    #pragma unroll
    for (int j = 0; j < 64; ++j) accv[j] = b2[j];
    #pragma unroll 4
    for (int i = 0; i < 64; ++i) {
        float z1 = b1[i] + st0*W1[i] + st1*W1[64+i] + st2*W1[128+i]
                 + st3*W1[192+i] + st4*W1[256+i];
        float hi = tanh_fast(z1);
        #pragma unroll
        for (int j4 = 0; j4 < 16; ++j4) {
            float4 w = W2v[i*16 + j4];
            accv[4*j4+0] = fmaf(hi, w.x, accv[4*j4+0]);
            accv[4*j4+1] = fmaf(hi, w.y, accv[4*j4+1]);
            accv[4*j4+2] = fmaf(hi, w.z, accv[4*j4+2]);
            accv[4*j4+3] = fmaf(hi, w.w, accv[4*j4+3]);
        }
    }
    float z3 = b3[0];
    #pragma unroll
    for (int j = 0; j < 64; ++j) {
        float h2 = tanh_fast(accv[j]); accv[j] = h2;
        z3 = fmaf(h2, W3[j], z3);
    }
    float sig = rcpf(1.f + __expf(-z3));
    #pragma unroll
    for (int j = 0; j < 64; ++j) {
        float h2 = accv[j];
        accv[j] = sig * W3[j] * (1.f - h2*h2);
    }
    float gs0 = 0.f, gs1 = 0.f, gs2 = 0.f, gs3 = 0.f, gs4 = 0.f;
    #pragma unroll 4
    for (int i = 0; i < 64; ++i) {
        float g0 = 0.f;
        #pragma unroll
        for (int j4 = 0; j4 < 16; ++j4) {
            float4 w = W2v[i*16 + j4];
            g0 += w.x*accv[4*j4+0] + w.y*accv[4*j4+1] + w.z*accv[4*j4+2] + w.w*accv[4*j4+3];
        }
        float z1 = b1[i] + st0*W1[i] + st1*W1[64+i] + st2*W1[128+i]
                 + st3*W1[192+i] + st4*W1[256+i];
        float h1 = tanh_fast(z1);
        float gz1 = g0 * (1.f - h1*h1);
        gs0 = fmaf(W1[i],     gz1, gs0);
        gs1 = fmaf(W1[64+i],  gz1, gs1);
        gs2 = fmaf(W1[128+i], gz1, gs2);
        gs3 = fmaf(W1[192+i], gz1, gs3);
        gs4 = fmaf(W1[256+i], gz1, gs4);
    }
    float gkb0 = 0.5f*(gs2*G.m2s0 - gs3*G.m1s0);
    float gkb1 = 0.5f*(gs2*G.m2s1 - gs3*G.m1s1);
    float gkb2 = 0.5f*(gs2*G.m2s2 - gs3*G.m1s2);
    float kbm1p = G.kb0*G.m1p0 + G.kb1*G.m1p1 + G.kb2*G.m1p2;
    float kbm2p = G.kb0*G.m2p0 + G.kb1*G.m2p1 + G.kb2*G.m2p2;
    float kbm1n = G.kb0*G.m1n0 + G.kb1*G.m1n1 + G.kb2*G.m1n2;
    float kbm2n = G.kb0*G.m2n0 + G.kb1*G.m2n1 + G.kb2*G.m2n2;
    float gthp = -gs4 - 0.5f*(gs2*kbm1p + gs3*kbm2p);
    float gthn =  gs4 - 0.5f*(gs2*kbm1n + gs3*kbm2n);
    float gcr0 = 2.f*gkb0*G.idenom, gcr1 = 2.f*gkb1*G.idenom, gcr2 = 2.f*gkb2*G.idenom;
    float gc = -(gkb0*G.kb0 + gkb1*G.kb1 + gkb2*G.kb2)*G.idenom;
    float gtp0 = G.tn1*gcr2 - G.tn2*gcr1 + gc*G.tn0;
    float gtp1 = G.tn2*gcr0 - G.tn0*gcr2 + gc*G.tn1;
    float gtp2 = G.tn0*gcr1 - G.tn1*gcr0 + gc*G.tn2;
    float gtn0 = gcr1*G.tp2 - gcr2*G.tp1 + gc*G.tp0;
    float gtn1 = gcr2*G.tp0 - gcr0*G.tp2 + gc*G.tp1;
    float gtn2 = gcr0*G.tp1 - gcr1*G.tp0 + gc*G.tp2;
    float gep0 = gtp0*G.ilp, gep1 = gtp1*G.ilp, gep2 = gtp2*G.ilp;
    float gilp = gtp0*G.ep0 + gtp1*G.ep1 + gtp2*G.ep2;
    float glp  = gs0*G.il0p - gilp*G.ilp*G.ilp;
    float tl   = glp*rcpf(G.lp);
    gep0 = fmaf(tl, G.ep0, gep0); gep1 = fmaf(tl, G.ep1, gep1); gep2 = fmaf(tl, G.ep2, gep2);
    float gen0 = gtn0*G.iln, gen1 = gtn1*G.iln, gen2 = gtn2*G.iln;
    float giln = gtn0*G.en0 + gtn1*G.en1 + gtn2*G.en2;
    float gln  = gs1*G.il0n - giln*G.iln*G.iln;
    float ul   = gln*rcpf(G.ln);
    gen0 = fmaf(ul, G.en0, gen0); gen1 = fmaf(ul, G.en1, gen1); gen2 = fmaf(ul, G.en2, gen2);
    float* oa = out + (size_t)b * (size_t)(2*ndof) + ndof;
    const size_t nd1 = (size_t)ndof + 1;
    int ni = spr[0], nj = spr[1], nk = spr[2];
    int di = 3*ni, dj = 3*nj, dk = 3*nk, dp = nodal + spr[3], dn = nodal + spr[4];
    atomicAdd(oa + di + 0, ( gep0) * rcpf(Mff[(size_t)(di+0)*nd1]));
    atomicAdd(oa + di + 1, ( gep1) * rcpf(Mff[(size_t)(di+1)*nd1]));
    atomicAdd(oa + di + 2, ( gep2) * rcpf(Mff[(size_t)(di+2)*nd1]));
    atomicAdd(oa + dj + 0, (gen0-gep0) * rcpf(Mff[(size_t)(dj+0)*nd1]));
    atomicAdd(oa + dj + 1, (gen1-gep1) * rcpf(Mff[(size_t)(dj+1)*nd1]));
    atomicAdd(oa + dj + 2, (gen2-gep2) * rcpf(Mff[(size_t)(dj+2)*nd1]));
    atomicAdd(oa + dk + 0, (-gen0) * rcpf(Mff[(size_t)(dk+0)*nd1]));
    atomicAdd(oa + dk + 1, (-gen1) * rcpf(Mff[(size_t)(dk+1)*nd1]));
    atomicAdd(oa + dk + 2, (-gen2) * rcpf(Mff[(size_t)(dk+2)*nd1]));
    atomicAdd(oa + dp, (-gthp) * rcpf(Mff[(size_t)dp*nd1]));
    atomicAdd(oa + dn, (-gthn) * rcpf(Mff[(size_t)dn*nd1]));
}

// out[:, :ndof] = v ; out[:, ndof:] = (f_ext - Cdd*v + gather(fs)) / Mdd
template<int GATHER>
__global__ void k_out(const float* __restrict__ x, const float* __restrict__ C,
                      const float* __restrict__ Mff, const float* __restrict__ fext,
                      const float* __restrict__ fs, float* __restrict__ out,
                      int B, int ndof, int nodal, int S) {
    int idx = blockIdx.x * blockDim.x + threadIdx.x;
    if (idx >= B * ndof) return;
    int b = idx / ndof;
    int d = idx - b * ndof;
    size_t row = (size_t)b * (size_t)(2 * ndof);
    const size_t nd1 = (size_t)ndof + 1;
    float vd = x[row + ndof + d];
    out[row + d] = vd;
    float acc = fext[d] - C[(size_t)d * nd1] * vd;
    if (GATHER) {
        const float* fsb = fs + (size_t)b * (size_t)(11 * S);
        if (d < nodal) {
            int n = d / 3, c = d - 3 * n;
            if (n < S)            acc += fsb[(size_t)(0 + c) * S + n];
            if (n >= 1 && n <= S) acc += fsb[(size_t)(3 + c) * S + n - 1];
            if (n >= 2)           acc += fsb[(size_t)(6 + c) * S + n - 2];
        } else {
            int e = d - nodal;
            if (e < S)  acc += fsb[(size_t)9 * S + e];
            if (e >= 1) acc += fsb[(size_t)10 * S + e - 1];
        }
    }
    out[row + ndof + d] = acc * rcpf(Mff[(size_t)d * nd1]);
}

extern "C" void kernel_launch(void* const* d_in, const int* in_sizes, int n_in,
                              void* d_out, int out_size, void* d_ws, size_t ws_size,
                              hipStream_t stream) {
    const float* x    = (const float*)d_in[1];
    const float* W1   = (const float*)d_in[2];
    const float* b1   = (const float*)d_in[3];
    const float* W2   = (const float*)d_in[4];
    const float* b2   = (const float*)d_in[5];
    const float* W3   = (const float*)d_in[6];
    const float* b3   = (const float*)d_in[7];
    const float* C    = (const float*)d_in[8];
    const float* Mff  = (const float*)d_in[9];
    const float* fext = (const float*)d_in[10];
    const float* l0e  = (const float*)d_in[11];
    const float* d1i  = (const float*)d_in[12];
    const float* d2i  = (const float*)d_in[13];
    const int* springs = (const int*)d_in[14];
    float* out = (float*)d_out;

    int ndof  = in_sizes[10];
    int E     = in_sizes[11];
    int S     = in_sizes[14] / 5;
    int nodal = ndof - E;
    int B     = in_sizes[1] / (2 * ndof);

    int totF = B * S;
    int totO = B * ndof;
    size_t ws_need = (size_t)B * (size_t)(11 * S) * sizeof(float);

    if (d_ws && ws_size >= ws_need) {
        float* fs = (float*)d_ws;
        int nblk = (totF + 63) / 64;   // 64 springs per block (4 waves x 16)
        k_force_mfma<<<nblk, 256, 0, stream>>>(x, W1, b1, W2, b2, W3, b3,
                                               l0e, d1i, d2i, springs, fs,
                                               B, S, ndof, nodal);
        k_out<1><<<(totO + 255) / 256, 256, 0, stream>>>(x, C, Mff, fext, fs, out,
                                                         B, ndof, nodal, S);
    } else {
        k_out<0><<<(totO + 255) / 256, 256, 0, stream>>>(x, C, Mff, fext, nullptr, out,
                                                         B, ndof, nodal, S);
        k_force_scalar<<<(totF + 255) / 256, 256, 0, stream>>>(x, W1, b1, W2, b2, W3, b3, Mff,
                                                               l0e, d1i, d2i, springs, out,
                                                               B, S, ndof, nodal);
    }
}

// Round 5
// 125.129 us; speedup vs baseline: 3.7773x; 1.2362x over previous
//
#include <hip/hip_runtime.h>

#define EPSF 1e-12f

typedef __attribute__((ext_vector_type(8))) short short8;
typedef __attribute__((ext_vector_type(4))) float f32x4;

__device__ __forceinline__ float rcpf(float x) { return __builtin_amdgcn_rcpf(x); }

// tanh(x) = 1 - 2/(1+e^{2x}); saturates correctly without clamping
__device__ __forceinline__ float tanh_fast(float x) {
    float e = __expf(2.f * x);
    return 1.f - 2.f * rcpf(e + 1.f);
}

union U8 { short8 s; unsigned int u[4]; };

__device__ __forceinline__ unsigned int hi2(float x, float y) {
    // (bf16_trunc(y) << 16) | bf16_trunc(x)
    return __builtin_amdgcn_perm(__float_as_uint(y), __float_as_uint(x), 0x07060302u);
}
__device__ __forceinline__ float resid(float x) {
    return x - __uint_as_float(__float_as_uint(x) & 0xFFFF0000u);
}
// elements in slot order: a[0..3] -> slots 0..3, b[0..3] -> slots 4..7
__device__ __forceinline__ void pack8v(f32x4 a, f32x4 b, short8& hs, short8& ls) {
    U8 H, L;
    H.u[0] = hi2(a[0], a[1]); H.u[1] = hi2(a[2], a[3]);
    H.u[2] = hi2(b[0], b[1]); H.u[3] = hi2(b[2], b[3]);
    L.u[0] = hi2(resid(a[0]), resid(a[1])); L.u[1] = hi2(resid(a[2]), resid(a[3]));
    L.u[2] = hi2(resid(b[0]), resid(b[1])); L.u[3] = hi2(resid(b[2]), resid(b[3]));
    hs = H.s; ls = L.s;
}

struct Geom {
    float st0, st1, st2, st3, st4;
    float ep0,ep1,ep2, en0,en1,en2;
    float lp, ln, ilp, iln, il0p, il0n, idenom;
    float tp0,tp1,tp2, tn0,tn1,tn2;
    float kb0,kb1,kb2;
    float m1p0,m1p1,m1p2, m2p0,m2p1,m2p2;
    float m1n0,m1n1,m1n2, m2n0,m2n1,m2n2;
    float m1s0,m1s1,m1s2, m2s0,m2s1,m2s2;
};

__device__ __forceinline__ Geom compute_geom(
        const float* __restrict__ q, const int* __restrict__ spr,
        const float* __restrict__ l0e, const float* __restrict__ d1i,
        const float* __restrict__ d2i, int nodal) {
    Geom G;
    int ni = spr[0], nj = spr[1], nk = spr[2], iep = spr[3], ien = spr[4];
    float xi0 = q[3*ni+0], xi1 = q[3*ni+1], xi2 = q[3*ni+2];
    float xj0 = q[3*nj+0], xj1 = q[3*nj+1], xj2 = q[3*nj+2];
    float xk0 = q[3*nk+0], xk1 = q[3*nk+1], xk2 = q[3*nk+2];
    float thp = q[nodal + iep], thn = q[nodal + ien];
    float l0p = l0e[iep], l0n = l0e[ien];
    float d1p0 = d1i[3*iep+0], d1p1 = d1i[3*iep+1], d1p2 = d1i[3*iep+2];
    float d2p0 = d2i[3*iep+0], d2p1 = d2i[3*iep+1], d2p2 = d2i[3*iep+2];
    float d1n0 = d1i[3*ien+0], d1n1 = d1i[3*ien+1], d1n2 = d1i[3*ien+2];
    float d2n0 = d2i[3*ien+0], d2n1 = d2i[3*ien+1], d2n2 = d2i[3*ien+2];

    G.ep0 = xj0-xi0; G.ep1 = xj1-xi1; G.ep2 = xj2-xi2;
    G.en0 = xk0-xj0; G.en1 = xk1-xj1; G.en2 = xk2-xj2;
    G.lp = sqrtf(G.ep0*G.ep0 + G.ep1*G.ep1 + G.ep2*G.ep2);
    G.ln = sqrtf(G.en0*G.en0 + G.en1*G.en1 + G.en2*G.en2);
    G.ilp = rcpf(G.lp + EPSF); G.iln = rcpf(G.ln + EPSF);
    G.tp0 = G.ep0*G.ilp; G.tp1 = G.ep1*G.ilp; G.tp2 = G.ep2*G.ilp;
    G.tn0 = G.en0*G.iln; G.tn1 = G.en1*G.iln; G.tn2 = G.en2*G.iln;
    float cdot = G.tp0*G.tn0 + G.tp1*G.tn1 + G.tp2*G.tn2;
    G.idenom = rcpf(1.f + cdot + EPSF);
    float cr0 = G.tp1*G.tn2 - G.tp2*G.tn1;
    float cr1 = G.tp2*G.tn0 - G.tp0*G.tn2;
    float cr2 = G.tp0*G.tn1 - G.tp1*G.tn0;
    G.kb0 = 2.f*cr0*G.idenom; G.kb1 = 2.f*cr1*G.idenom; G.kb2 = 2.f*cr2*G.idenom;
    float cp, sp; __sincosf(thp, &sp, &cp);
    float cn, sn; __sincosf(thn, &sn, &cn);
    G.m1p0 = cp*d1p0 + sp*d2p0; G.m1p1 = cp*d1p1 + sp*d2p1; G.m1p2 = cp*d1p2 + sp*d2p2;
    G.m2p0 = cp*d2p0 - sp*d1p0; G.m2p1 = cp*d2p1 - sp*d1p1; G.m2p2 = cp*d2p2 - sp*d1p2;
    G.m1n0 = cn*d1n0 + sn*d2n0; G.m1n1 = cn*d1n1 + sn*d2n1; G.m1n2 = cn*d1n2 + sn*d2n2;
    G.m2n0 = cn*d2n0 - sn*d1n0; G.m2n1 = cn*d2n1 - sn*d1n1; G.m2n2 = cn*d2n2 - sn*d1n2;
    G.m1s0 = G.m1p0+G.m1n0; G.m1s1 = G.m1p1+G.m1n1; G.m1s2 = G.m1p2+G.m1n2;
    G.m2s0 = G.m2p0+G.m2n0; G.m2s1 = G.m2p1+G.m2n1; G.m2s2 = G.m2p2+G.m2n2;
    G.il0p = rcpf(l0p); G.il0n = rcpf(l0n);
    G.st0 = G.lp*G.il0p - 1.f;
    G.st1 = G.ln*G.il0n - 1.f;
    G.st2 =  0.5f*(G.kb0*G.m2s0 + G.kb1*G.m2s1 + G.kb2*G.m2s2);
    G.st3 = -0.5f*(G.kb0*G.m1s0 + G.kb1*G.m1s1 + G.kb2*G.m1s2);
    G.st4 = thn - thp;
    return G;
}

// geometry backward from gs[5]; writes 11 force slots (slot-major)
__device__ __forceinline__ void geom_backward_store(
        const Geom& G, const float gs0, const float gs1, const float gs2,
        const float gs3, const float gs4, float* __restrict__ fsb, int S) {
    float gkb0 = 0.5f*(gs2*G.m2s0 - gs3*G.m1s0);
    float gkb1 = 0.5f*(gs2*G.m2s1 - gs3*G.m1s1);
    float gkb2 = 0.5f*(gs2*G.m2s2 - gs3*G.m1s2);

    float kbm1p = G.kb0*G.m1p0 + G.kb1*G.m1p1 + G.kb2*G.m1p2;
    float kbm2p = G.kb0*G.m2p0 + G.kb1*G.m2p1 + G.kb2*G.m2p2;
    float kbm1n = G.kb0*G.m1n0 + G.kb1*G.m1n1 + G.kb2*G.m1n2;
    float kbm2n = G.kb0*G.m2n0 + G.kb1*G.m2n1 + G.kb2*G.m2n2;
    float gthp = -gs4 - 0.5f*(gs2*kbm1p + gs3*kbm2p);
    float gthn =  gs4 - 0.5f*(gs2*kbm1n + gs3*kbm2n);

    float gcr0 = 2.f*gkb0*G.idenom, gcr1 = 2.f*gkb1*G.idenom, gcr2 = 2.f*gkb2*G.idenom;
    float gc = -(gkb0*G.kb0 + gkb1*G.kb1 + gkb2*G.kb2)*G.idenom;

    float gtp0 = G.tn1*gcr2 - G.tn2*gcr1 + gc*G.tn0;
    float gtp1 = G.tn2*gcr0 - G.tn0*gcr2 + gc*G.tn1;
    float gtp2 = G.tn0*gcr1 - G.tn1*gcr0 + gc*G.tn2;
    float gtn0 = gcr1*G.tp2 - gcr2*G.tp1 + gc*G.tp0;
    float gtn1 = gcr2*G.tp0 - gcr0*G.tp2 + gc*G.tp1;
    float gtn2 = gcr0*G.tp1 - gcr1*G.tp0 + gc*G.tp2;

    float gep0 = gtp0*G.ilp, gep1 = gtp1*G.ilp, gep2 = gtp2*G.ilp;
    float gilp = gtp0*G.ep0 + gtp1*G.ep1 + gtp2*G.ep2;
    float glp  = gs0*G.il0p - gilp*G.ilp*G.ilp;
    float tl   = glp*rcpf(G.lp);
    gep0 = fmaf(tl, G.ep0, gep0); gep1 = fmaf(tl, G.ep1, gep1); gep2 = fmaf(tl, G.ep2, gep2);

    float gen0 = gtn0*G.iln, gen1 = gtn1*G.iln, gen2 = gtn2*G.iln;
    float giln = gtn0*G.en0 + gtn1*G.en1 + gtn2*G.en2;
    float gln  = gs1*G.il0n - giln*G.iln*G.iln;
    float ul   = gln*rcpf(G.ln);
    gen0 = fmaf(ul, G.en0, gen0); gen1 = fmaf(ul, G.en1, gen1); gen2 = fmaf(ul, G.en2, gen2);

    fsb[0*(size_t)S] = gep0;        fsb[1*(size_t)S] = gep1;        fsb[2*(size_t)S] = gep2;
    fsb[3*(size_t)S] = gen0-gep0;   fsb[4*(size_t)S] = gen1-gep1;   fsb[5*(size_t)S] = gen2-gep2;
    fsb[6*(size_t)S] = -gen0;       fsb[7*(size_t)S] = -gen1;       fsb[8*(size_t)S] = -gen2;
    fsb[9*(size_t)S] = -gthp;       fsb[10*(size_t)S] = -gthn;
}

#define MFMA_BF16 __builtin_amdgcn_mfma_f32_16x16x32_bf16

// ---------------- MFMA force kernel (wave = 16 springs) ----------------
// spring = lane&15; 4 lane-groups g4 = lane>>4 co-own each spring.
// W2 is staged in LDS in MFMA-FRAGMENT ORDER: the A-fragment for
// (tile, kc) lives at [(tile*2+kc)*64 + lane]*16B -> every wave read is
// base(lane*16) + constant offset: linear, bank-conflict-free ds_read_b128.
// Slot convention (lambda): slot j of lane-group g4 in chunk kc holds
// k = kc*32 + 16*(j>>2) + 4*g4 + (j&3); identical for A (staging) and B
// (pack8v order) => correct for any true HW k-map.
__global__ __launch_bounds__(256) void k_force_mfma(
    const float* __restrict__ x,
    const float* __restrict__ W1, const float* __restrict__ b1,
    const float* __restrict__ W2, const float* __restrict__ b2,
    const float* __restrict__ W3, const float* __restrict__ b3,
    const float* __restrict__ l0e,
    const float* __restrict__ d1i, const float* __restrict__ d2i,
    const int* __restrict__ springs,
    float* __restrict__ fs,
    int B, int S, int ndof, int nodal)
{
    __shared__ short sAf[2][4096];   // fwd A = W2^T, [hi/lo], frag-order
    __shared__ short sAb[2][4096];   // bwd A = W2,   [hi/lo], frag-order
    __shared__ float sPar[520];      // [0]W1(320) [320]b1 [384]b2 [448]W3 [512]b3

    const int t = threadIdx.x;
    #pragma unroll
    for (int e = 0; e < 16; ++e) {
        int L = t + 256*e;             // L = i*64 + o
        float w = W2[L];
        unsigned int u = __float_as_uint(w);
        short hsv = (short)(u >> 16);
        float lo = w - __uint_as_float(u & 0xFFFF0000u);
        short lsv = (short)(__float_as_uint(lo) >> 16);
        int i = L >> 6, o = L & 63;
        // fwd: A=W2^T, row o, k=i
        int posf = ((o >> 4)*2 + (i >> 5))*512
                 + (((i >> 2) & 3)*16 + (o & 15))*8
                 + ((i >> 4) & 1)*4 + (i & 3);
        sAf[0][posf] = hsv; sAf[1][posf] = lsv;
        // bwd: A=W2, row i, k=o
        int posb = ((i >> 4)*2 + (o >> 5))*512
                 + (((o >> 2) & 3)*16 + (i & 15))*8
                 + ((o >> 4) & 1)*4 + (o & 3);
        sAb[0][posb] = hsv; sAb[1][posb] = lsv;
    }
    for (int u2 = t; u2 < 320; u2 += 256) sPar[u2] = W1[u2];
    if (t < 64) { sPar[320+t] = b1[t]; sPar[384+t] = b2[t]; sPar[448+t] = W3[t]; }
    if (t == 0) sPar[512] = b3[0];
    __syncthreads();

    const int lane = t & 63;
    const int wv = t >> 6;
    const int g4 = lane >> 4;          // lane-group 0..3
    const int m16 = lane & 15;         // spring within wave / MFMA row-col index

    int sp = (blockIdx.x * 4 + wv) * 16 + m16;
    const bool active = sp < B * S;
    int spc = active ? sp : 0;
    int b = spc / S;
    int s = spc - b * S;
    const int* spr = springs + 5 * s;
    const float* q = x + (size_t)b * (size_t)(2 * ndof);

    // ---- geometry ONCE; carried in registers through the MLP ----
    Geom G = compute_geom(q, spr, l0e, d1i, d2i, nodal);

    // ---- h1 at i = 16*it + 4*g4 + r (16 tanh per lane) ----
    f32x4 h1v[4];
    #pragma unroll
    for (int it = 0; it < 4; ++it) {
        const int off = it*16 + g4*4;
        f32x4 b1f = *(const f32x4*)&sPar[320 + off];
        f32x4 wa = *(const f32x4*)&sPar[0*64 + off];
        f32x4 wb = *(const f32x4*)&sPar[1*64 + off];
        f32x4 wc = *(const f32x4*)&sPar[2*64 + off];
        f32x4 wd = *(const f32x4*)&sPar[3*64 + off];
        f32x4 we = *(const f32x4*)&sPar[4*64 + off];
        #pragma unroll
        for (int r = 0; r < 4; ++r) {
            float z1 = b1f[r] + G.st0*wa[r] + G.st1*wb[r] + G.st2*wc[r]
                     + G.st3*wd[r] + G.st4*we[r];
            h1v[it][r] = tanh_fast(z1);
        }
    }

    // ---- pack h1 into B fragments (slot order = lambda by construction) ----
    short8 bh0, bl0, bh1, bl1;
    pack8v(h1v[0], h1v[1], bh0, bl0);   // kc=0: it 0,1
    pack8v(h1v[2], h1v[3], bh1, bl1);   // kc=1: it 2,3

    // ---- forward: z2^T[o][spring], acc[ot] covers o = ot*16 + 4*g4 + r ----
    const short8* Afh = (const short8*)&sAf[0][0];
    const short8* Afl = (const short8*)&sAf[1][0];
    f32x4 acc[4];
    #pragma unroll
    for (int ot = 0; ot < 4; ++ot)
        acc[ot] = *(const f32x4*)&sPar[384 + ot*16 + g4*4];

    #pragma unroll
    for (int ot = 0; ot < 4; ++ot) {
        short8 ah0 = Afh[(ot*2+0)*64 + lane];
        short8 al0 = Afl[(ot*2+0)*64 + lane];
        short8 ah1 = Afh[(ot*2+1)*64 + lane];
        short8 al1 = Afl[(ot*2+1)*64 + lane];
        acc[ot] = MFMA_BF16(ah0, bh0, acc[ot], 0, 0, 0);
        acc[ot] = MFMA_BF16(ah0, bl0, acc[ot], 0, 0, 0);
        acc[ot] = MFMA_BF16(al0, bh0, acc[ot], 0, 0, 0);
        acc[ot] = MFMA_BF16(ah1, bh1, acc[ot], 0, 0, 0);
        acc[ot] = MFMA_BF16(ah1, bl1, acc[ot], 0, 0, 0);
        acc[ot] = MFMA_BF16(al1, bh1, acc[ot], 0, 0, 0);
    }

    // ---- middle: h2 = tanh(z2); z3 = h2.W3 (+2 shfl); sig; gz2 in place ----
    f32x4 w3v[4];
    #pragma unroll
    for (int ot = 0; ot < 4; ++ot)
        w3v[ot] = *(const f32x4*)&sPar[448 + ot*16 + g4*4];

    float z3 = 0.f;
    #pragma unroll
    for (int ot = 0; ot < 4; ++ot)
        #pragma unroll
        for (int r = 0; r < 4; ++r) {
            float h2 = tanh_fast(acc[ot][r]);
            acc[ot][r] = h2;
            z3 = fmaf(h2, w3v[ot][r], z3);
        }
    z3 += __shfl_xor(z3, 16, 64);
    z3 += __shfl_xor(z3, 32, 64);
    z3 += sPar[512];
    float sig = rcpf(1.f + __expf(-z3));       // softplus'

    #pragma unroll
    for (int ot = 0; ot < 4; ++ot)
        #pragma unroll
        for (int r = 0; r < 4; ++r) {
            float h2 = acc[ot][r];
            acc[ot][r] = sig * w3v[ot][r] * (1.f - h2*h2);
        }

    // ---- backward: g[i][spring] = W2 @ gz2 ; B feeds directly from acc ----
    pack8v(acc[0], acc[1], bh0, bl0);   // kc=0: o-tiles 0,1
    pack8v(acc[2], acc[3], bh1, bl1);   // kc=1: o-tiles 2,3

    const short8* Abh = (const short8*)&sAb[0][0];
    const short8* Abl = (const short8*)&sAb[1][0];
    f32x4 gg[4];
    #pragma unroll
    for (int it = 0; it < 4; ++it) gg[it] = (f32x4){0.f, 0.f, 0.f, 0.f};

    #pragma unroll
    for (int it = 0; it < 4; ++it) {
        short8 ah0 = Abh[(it*2+0)*64 + lane];
        short8 al0 = Abl[(it*2+0)*64 + lane];
        short8 ah1 = Abh[(it*2+1)*64 + lane];
        short8 al1 = Abl[(it*2+1)*64 + lane];
        gg[it] = MFMA_BF16(ah0, bh0, gg[it], 0, 0, 0);
        gg[it] = MFMA_BF16(ah0, bl0, gg[it], 0, 0, 0);
        gg[it] = MFMA_BF16(al0, bh0, gg[it], 0, 0, 0);
        gg[it] = MFMA_BF16(ah1, bh1, gg[it], 0, 0, 0);
        gg[it] = MFMA_BF16(ah1, bl1, gg[it], 0, 0, 0);
        gg[it] = MFMA_BF16(al1, bh1, gg[it], 0, 0, 0);
    }

    // ---- gz1 = g*(1-h1^2) (h1 already at C positions); gs partials; reduce ----
    float p0 = 0.f, p1 = 0.f, p2 = 0.f, p3 = 0.f, p4 = 0.f;
    #pragma unroll
    for (int it = 0; it < 4; ++it) {
        const int off = it*16 + g4*4;
        f32x4 wa = *(const f32x4*)&sPar[0*64 + off];
        f32x4 wb = *(const f32x4*)&sPar[1*64 + off];
        f32x4 wc = *(const f32x4*)&sPar[2*64 + off];
        f32x4 wd = *(const f32x4*)&sPar[3*64 + off];
        f32x4 we = *(const f32x4*)&sPar[4*64 + off];
        #pragma unroll
        for (int r = 0; r < 4; ++r) {
            float hv = h1v[it][r];
            float gz1 = gg[it][r] * (1.f - hv*hv);
            p0 = fmaf(gz1, wa[r], p0);
            p1 = fmaf(gz1, wb[r], p1);
            p2 = fmaf(gz1, wc[r], p2);
            p3 = fmaf(gz1, wd[r], p3);
            p4 = fmaf(gz1, we[r], p4);
        }
    }
    p0 += __shfl_xor(p0, 16, 64); p0 += __shfl_xor(p0, 32, 64);
    p1 += __shfl_xor(p1, 16, 64); p1 += __shfl_xor(p1, 32, 64);
    p2 += __shfl_xor(p2, 16, 64); p2 += __shfl_xor(p2, 32, 64);
    p3 += __shfl_xor(p3, 16, 64); p3 += __shfl_xor(p3, 32, 64);
    p4 += __shfl_xor(p4, 16, 64); p4 += __shfl_xor(p4, 32, 64);

    // ---- geometry backward + store (one lane-group per spring) ----
    if (active && g4 == 0) {
        float* fsb = fs + (size_t)b * (size_t)(11 * S) + s;
        geom_backward_store(G, p0, p1, p2, p3, p4, fsb, S);
    }
}

// ---------------- fallback: scalar per-thread kernel with atomics ----------------
__global__ __launch_bounds__(256) void k_force_scalar(
    const float* __restrict__ x,
    const float* __restrict__ W1, const float* __restrict__ b1,
    const float* __restrict__ W2, const float* __restrict__ b2,
    const float* __restrict__ W3, const float* __restrict__ b3,
    const float* __restrict__ Mff,
    const float* __restrict__ l0e,
    const float* __restrict__ d1i, const float* __restrict__ d2i,
    const int* __restrict__ springs,
    float* __restrict__ out,
    int B, int S, int ndof, int nodal)
{
    int tid = blockIdx.x * 256 + threadIdx.x;
    if (tid >= B * S) return;
    int b = tid / S;
    int s = tid - b * S;
    const int* spr = springs + 5 * s;
    const float* q = x + (size_t)b * (size_t)(2 * ndof);
    Geom G = compute_geom(q, spr, l0e, d1i, d2i, nodal);
    float st0 = G.st0, st1 = G.st1, st2 = G.st2, st3 = G.st3, st4 = G.st4;

    const float4* W2v = reinterpret_cast<const float4*>(W2);
    float accv[64];
    #pragma unroll
    for (int j = 0; j < 64; ++j) accv[j] = b2[j];
    #pragma unroll 4
    for (int i = 0; i < 64; ++i) {
        float z1 = b1[i] + st0*W1[i] + st1*W1[64+i] + st2*W1[128+i]
                 + st3*W1[192+i] + st4*W1[256+i];
        float hi = tanh_fast(z1);
        #pragma unroll
        for (int j4 = 0; j4 < 16; ++j4) {
            float4 w = W2v[i*16 + j4];
            accv[4*j4+0] = fmaf(hi, w.x, accv[4*j4+0]);
            accv[4*j4+1] = fmaf(hi, w.y, accv[4*j4+1]);
            accv[4*j4+2] = fmaf(hi, w.z, accv[4*j4+2]);
            accv[4*j4+3] = fmaf(hi, w.w, accv[4*j4+3]);
        }
    }
    float z3 = b3[0];
    #pragma unroll
    for (int j = 0; j < 64; ++j) {
        float h2 = tanh_fast(accv[j]); accv[j] = h2;
        z3 = fmaf(h2, W3[j], z3);
    }
    float sig = rcpf(1.f + __expf(-z3));
    #pragma unroll
    for (int j = 0; j < 64; ++j) {
        float h2 = accv[j];
        accv[j] = sig * W3[j] * (1.f - h2*h2);
    }
    float gs0 = 0.f, gs1 = 0.f, gs2 = 0.f, gs3 = 0.f, gs4 = 0.f;
    #pragma unroll 4
    for (int i = 0; i < 64; ++i) {
        float g0 = 0.f;
        #pragma unroll
        for (int j4 = 0; j4 < 16; ++j4) {
            float4 w = W2v[i*16 + j4];
            g0 += w.x*accv[4*j4+0] + w.y*accv[4*j4+1] + w.z*accv[4*j4+2] + w.w*accv[4*j4+3];
        }
        float z1 = b1[i] + st0*W1[i] + st1*W1[64+i] + st2*W1[128+i]
                 + st3*W1[192+i] + st4*W1[256+i];
        float h1 = tanh_fast(z1);
        float gz1 = g0 * (1.f - h1*h1);
        gs0 = fmaf(W1[i],     gz1, gs0);
        gs1 = fmaf(W1[64+i],  gz1, gs1);
        gs2 = fmaf(W1[128+i], gz1, gs2);
        gs3 = fmaf(W1[192+i], gz1, gs3);
        gs4 = fmaf(W1[256+i], gz1, gs4);
    }
    float gkb0 = 0.5f*(gs2*G.m2s0 - gs3*G.m1s0);
    float gkb1 = 0.5f*(gs2*G.m2s1 - gs3*G.m1s1);
    float gkb2 = 0.5f*(gs2*G.m2s2 - gs3*G.m1s2);
    float kbm1p = G.kb0*G.m1p0 + G.kb1*G.m1p1 + G.kb2*G.m1p2;
    float kbm2p = G.kb0*G.m2p0 + G.kb1*G.m2p1 + G.kb2*G.m2p2;
    float kbm1n = G.kb0*G.m1n0 + G.kb1*G.m1n1 + G.kb2*G.m1n2;
    float kbm2n = G.kb0*G.m2n0 + G.kb1*G.m2n1 + G.kb2*G.m2n2;
    float gthp = -gs4 - 0.5f*(gs2*kbm1p + gs3*kbm2p);
    float gthn =  gs4 - 0.5f*(gs2*kbm1n + gs3*kbm2n);
    float gcr0 = 2.f*gkb0*G.idenom, gcr1 = 2.f*gkb1*G.idenom, gcr2 = 2.f*gkb2*G.idenom;
    float gc = -(gkb0*G.kb0 + gkb1*G.kb1 + gkb2*G.kb2)*G.idenom;
    float gtp0 = G.tn1*gcr2 - G.tn2*gcr1 + gc*G.tn0;
    float gtp1 = G.tn2*gcr0 - G.tn0*gcr2 + gc*G.tn1;
    float gtp2 = G.tn0*gcr1 - G.tn1*gcr0 + gc*G.tn2;
    float gtn0 = gcr1*G.tp2 - gcr2*G.tp1 + gc*G.tp0;
    float gtn1 = gcr2*G.tp0 - gcr0*G.tp2 + gc*G.tp1;
    float gtn2 = gcr0*G.tp1 - gcr1*G.tp0 + gc*G.tp2;
    float gep0 = gtp0*G.ilp, gep1 = gtp1*G.ilp, gep2 = gtp2*G.ilp;
    float gilp = gtp0*G.ep0 + gtp1*G.ep1 + gtp2*G.ep2;
    float glp  = gs0*G.il0p - gilp*G.ilp*G.ilp;
    float tl   = glp*rcpf(G.lp);
    gep0 = fmaf(tl, G.ep0, gep0); gep1 = fmaf(tl, G.ep1, gep1); gep2 = fmaf(tl, G.ep2, gep2);
    float gen0 = gtn0*G.iln, gen1 = gtn1*G.iln, gen2 = gtn2*G.iln;
    float giln = gtn0*G.en0 + gtn1*G.en1 + gtn2*G.en2;
    float gln  = gs1*G.il0n - giln*G.iln*G.iln;
    float ul   = gln*rcpf(G.ln);
    gen0 = fmaf(ul, G.en0, gen0); gen1 = fmaf(ul, G.en1, gen1); gen2 = fmaf(ul, G.en2, gen2);
    float* oa = out + (size_t)b * (size_t)(2*ndof) + ndof;
    const size_t nd1 = (size_t)ndof + 1;
    int ni = spr[0], nj = spr[1], nk = spr[2];
    int di = 3*ni, dj = 3*nj, dk = 3*nk, dp = nodal + spr[3], dn = nodal + spr[4];
    atomicAdd(oa + di + 0, ( gep0) * rcpf(Mff[(size_t)(di+0)*nd1]));
    atomicAdd(oa + di + 1, ( gep1) * rcpf(Mff[(size_t)(di+1)*nd1]));
    atomicAdd(oa + di + 2, ( gep2) * rcpf(Mff[(size_t)(di+2)*nd1]));
    atomicAdd(oa + dj + 0, (gen0-gep0) * rcpf(Mff[(size_t)(dj+0)*nd1]));
    atomicAdd(oa + dj + 1, (gen1-gep1) * rcpf(Mff[(size_t)(dj+1)*nd1]));
    atomicAdd(oa + dj + 2, (gen2-gep2) * rcpf(Mff[(size_t)(dj+2)*nd1]));
    atomicAdd(oa + dk + 0, (-gen0) * rcpf(Mff[(size_t)(dk+0)*nd1]));
    atomicAdd(oa + dk + 1, (-gen1) * rcpf(Mff[(size_t)(dk+1)*nd1]));
    atomicAdd(oa + dk + 2, (-gen2) * rcpf(Mff[(size_t)(dk+2)*nd1]));
    atomicAdd(oa + dp, (-gthp) * rcpf(Mff[(size_t)dp*nd1]));
    atomicAdd(oa + dn, (-gthn) * rcpf(Mff[(size_t)dn*nd1]));
}

// out[:, :ndof] = v ; out[:, ndof:] = (f_ext - Cdd*v + gather(fs)) / Mdd
template<int GATHER>
__global__ void k_out(const float* __restrict__ x, const float* __restrict__ C,
                      const float* __restrict__ Mff, const float* __restrict__ fext,
                      const float* __restrict__ fs, float* __restrict__ out,
                      int B, int ndof, int nodal, int S) {
    int idx = blockIdx.x * blockDim.x + threadIdx.x;
    if (idx >= B * ndof) return;
    int b = idx / ndof;
    int d = idx - b * ndof;
    size_t row = (size_t)b * (size_t)(2 * ndof);
    const size_t nd1 = (size_t)ndof + 1;
    float vd = x[row + ndof + d];
    out[row + d] = vd;
    float acc = fext[d] - C[(size_t)d * nd1] * vd;
    if (GATHER) {
        const float* fsb = fs + (size_t)b * (size_t)(11 * S);
        if (d < nodal) {
            int n = d / 3, c = d - 3 * n;
            if (n < S)            acc += fsb[(size_t)(0 + c) * S + n];
            if (n >= 1 && n <= S) acc += fsb[(size_t)(3 + c) * S + n - 1];
            if (n >= 2)           acc += fsb[(size_t)(6 + c) * S + n - 2];
        } else {
            int e = d - nodal;
            if (e < S)  acc += fsb[(size_t)9 * S + e];
            if (e >= 1) acc += fsb[(size_t)10 * S + e - 1];
        }
    }
    out[row + ndof + d] = acc * rcpf(Mff[(size_t)d * nd1]);
}

extern "C" void kernel_launch(void* const* d_in, const int* in_sizes, int n_in,
                              void* d_out, int out_size, void* d_ws, size_t ws_size,
                              hipStream_t stream) {
    const float* x    = (const float*)d_in[1];
    const float* W1   = (const float*)d_in[2];
    const float* b1   = (const float*)d_in[3];
    const float* W2   = (const float*)d_in[4];
    const float* b2   = (const float*)d_in[5];
    const float* W3   = (const float*)d_in[6];
    const float* b3   = (const float*)d_in[7];
    const float* C    = (const float*)d_in[8];
    const float* Mff  = (const float*)d_in[9];
    const float* fext = (const float*)d_in[10];
    const float* l0e  = (const float*)d_in[11];
    const float* d1i  = (const float*)d_in[12];
    const float* d2i  = (const float*)d_in[13];
    const int* springs = (const int*)d_in[14];
    float* out = (float*)d_out;

    int ndof  = in_sizes[10];
    int E     = in_sizes[11];
    int S     = in_sizes[14] / 5;
    int nodal = ndof - E;
    int B     = in_sizes[1] / (2 * ndof);

    int totF = B * S;
    int totO = B * ndof;
    size_t ws_need = (size_t)B * (size_t)(11 * S) * sizeof(float);

    if (d_ws && ws_size >= ws_need) {
        float* fs = (float*)d_ws;
        int nblk = (totF + 63) / 64;   // 64 springs per block (4 waves x 16)
        k_force_mfma<<<nblk, 256, 0, stream>>>(x, W1, b1, W2, b2, W3, b3,
                                               l0e, d1i, d2i, springs, fs,
                                               B, S, ndof, nodal);
        k_out<1><<<(totO + 255) / 256, 256, 0, stream>>>(x, C, Mff, fext, fs, out,
                                                         B, ndof, nodal, S);
    } else {
        k_out<0><<<(totO + 255) / 256, 256, 0, stream>>>(x, C, Mff, fext, nullptr, out,
                                                         B, ndof, nodal, S);
        k_force_scalar<<<(totF + 255) / 256, 256, 0, stream>>>(x, W1, b1, W2, b2, W3, b3, Mff,
                                                               l0e, d1i, d2i, springs, out,
                                                               B, S, ndof, nodal);
    }
}